// Round 1
// baseline (33185.721 us; speedup 1.0000x reference)
//
#include <hip/hip_runtime.h>
#include <stdint.h>

#define E   512
#define H   8
#define DH  64
#define BB  8
#define SS  24
#define FF  2048
#define NL  3
#define VTOK 32000
#define LBUF 25
#define ML  24
#define START_ID 1

// ---------------------------------------------------------------------------
// Encoder embedding + sinusoidal PE (PE computed in double to match numpy)
// grid: (S*B) blocks, 256 threads. row r = s*B + b (seq-first layout).
// ---------------------------------------------------------------------------
__global__ void enc_embed_kernel(const int* __restrict__ inp, const float* __restrict__ emb,
                                 float* __restrict__ x) {
  int r = blockIdx.x;
  int s = r / BB, b = r % BB;
  int tok = inp[b * SS + s];
  const float* er = emb + (size_t)tok * E;
  for (int e = threadIdx.x; e < E; e += blockDim.x) {
    int j = e >> 1;
    double dv = exp(-((double)(2 * j)) * (log(10000.0) / (double)E));
    double ang = (double)s * dv;
    double pe = (e & 1) ? cos(ang) : sin(ang);
    x[(size_t)r * E + e] = er[e] + (float)pe;
  }
}

// ---------------------------------------------------------------------------
// Row LayerNorm: grid = rows, block = 256 (E=512: 2 elems/thread)
// ---------------------------------------------------------------------------
__global__ void ln_kernel(const float* __restrict__ x, const float* __restrict__ g,
                          const float* __restrict__ bta, float* __restrict__ y) {
  int r = blockIdx.x;
  int t = threadIdx.x;
  const float* xr = x + (size_t)r * E;
  float a0 = xr[t], a1 = xr[t + 256];
  __shared__ float red[256];
  red[t] = a0 + a1;
  __syncthreads();
  for (int s = 128; s > 0; s >>= 1) { if (t < s) red[t] += red[t + s]; __syncthreads(); }
  float m = red[0] * (1.0f / (float)E);
  __syncthreads();
  float d0 = a0 - m, d1 = a1 - m;
  red[t] = d0 * d0 + d1 * d1;
  __syncthreads();
  for (int s = 128; s > 0; s >>= 1) { if (t < s) red[t] += red[t + s]; __syncthreads(); }
  float v = red[0] * (1.0f / (float)E);
  float rstd = 1.0f / sqrtf(v + 1e-5f);
  y[(size_t)r * E + t]       = d0 * rstd * g[t]       + bta[t];
  y[(size_t)r * E + t + 256] = d1 * rstd * g[t + 256] + bta[t + 256];
}

// ---------------------------------------------------------------------------
// Encoder GEMM: C[M,N] = A[M,K] @ W[K,N] + bias (+resid)(relu?)
// grid (M, N/256), block 256. A row cached in LDS; W reads coalesced.
// ---------------------------------------------------------------------------
__global__ void gemm_rows_kernel(const float* __restrict__ A, int lda, int K,
                                 const float* __restrict__ W, int ldw,
                                 const float* __restrict__ bias,
                                 const float* __restrict__ resid,
                                 float* __restrict__ C, int ldc, int N, int relu) {
  __shared__ float Ar[2048];
  int m = blockIdx.x;
  int col = blockIdx.y * 256 + threadIdx.x;
  for (int k = threadIdx.x; k < K; k += 256) Ar[k] = A[(size_t)m * lda + k];
  __syncthreads();
  if (col >= N) return;
  float acc = bias[col];
  const float* wp = W + col;
  for (int k = 0; k < K; ++k) acc += Ar[k] * wp[(size_t)k * ldw];
  if (resid) acc += resid[(size_t)m * ldc + col];
  if (relu) acc = fmaxf(acc, 0.0f);
  C[(size_t)m * ldc + col] = acc;
}

// ---------------------------------------------------------------------------
// Decoder GEMM, M=8 rows: all rows in LDS, each weight element read once,
// 8 outputs per weight load. Optional fused block-argmax -> atomicMax.
// grid (N/256), block 256.
// ---------------------------------------------------------------------------
__global__ void gemm_m8_kernel(const float* __restrict__ A, int lda, int K,
                               const float* __restrict__ W, int ldw,
                               const float* __restrict__ bias,
                               const float* __restrict__ resid,
                               float* __restrict__ C, int ldc, int N, int relu,
                               unsigned long long* __restrict__ amax) {
  __shared__ float Al[8 * 2048];   // 64 KB
  int t = threadIdx.x;
  for (int idx = t; idx < 8 * K; idx += 256) {
    int m = idx / K, k = idx - m * K;
    Al[idx] = A[(size_t)m * lda + k];
  }
  __syncthreads();
  int col = blockIdx.x * 256 + t;
  float acc[8];
  if (col < N) {
    float bv = bias[col];
#pragma unroll
    for (int m = 0; m < 8; ++m) acc[m] = bv;
    const float* wp = W + col;
    for (int k = 0; k < K; ++k) {
      float w = wp[(size_t)k * ldw];
#pragma unroll
      for (int m = 0; m < 8; ++m) acc[m] += Al[m * K + k] * w;
    }
#pragma unroll
    for (int m = 0; m < 8; ++m) {
      float v = acc[m];
      if (resid) v += resid[(size_t)m * ldc + col];
      if (relu) v = fmaxf(v, 0.0f);
      acc[m] = v;
      C[(size_t)m * ldc + col] = v;
    }
  }
  if (amax) {
    __syncthreads();                             // done with Al; reuse as reduce buf
    unsigned long long* red = (unsigned long long*)Al;
    for (int m = 0; m < 8; ++m) {
      unsigned long long key = 0ull;
      if (col < N) {
        unsigned int fb = __float_as_uint(acc[m]);
        fb = (fb & 0x80000000u) ? ~fb : (fb | 0x80000000u);   // order-preserving
        key = ((unsigned long long)fb << 32) |
              (unsigned long long)(0xFFFFFFFFu - (unsigned)col); // first-index tiebreak
      }
      red[t] = key;
      __syncthreads();
      for (int s = 128; s > 0; s >>= 1) {
        if (t < s) red[t] = red[t] > red[t + s] ? red[t] : red[t + s];
        __syncthreads();
      }
      if (t == 0) atomicMax(&amax[m], red[0]);
      __syncthreads();
    }
  }
}

// ---------------------------------------------------------------------------
// Encoder self-attention: block per (b,h), 256 threads. Lq=Lk=24, D=64.
// qkv layout: [s*B+b, 3E], q|k|v at col offsets 0|E|2E, head h at +h*64.
// ---------------------------------------------------------------------------
__global__ void enc_attn_kernel(const float* __restrict__ qkv, float* __restrict__ o) {
  int b = blockIdx.x >> 3, h = blockIdx.x & 7;
  __shared__ float qs[SS * DH], ks[SS * DH], vs[SS * DH];
  __shared__ float sc[SS][SS];
  int t = threadIdx.x;
  for (int idx = t; idx < SS * DH; idx += 256) {
    int srow = idx / DH, d = idx - srow * DH;
    size_t base = ((size_t)(srow * BB + b)) * (3 * E) + h * DH + d;
    qs[idx] = qkv[base];
    ks[idx] = qkv[base + E];
    vs[idx] = qkv[base + 2 * E];
  }
  __syncthreads();
  for (int p = t; p < SS * SS; p += 256) {
    int qi = p / SS, kj = p - qi * SS;
    float a = 0.f;
    for (int d = 0; d < DH; ++d) a += qs[qi * DH + d] * ks[kj * DH + d];
    sc[qi][kj] = a * 0.125f;
  }
  __syncthreads();
  if (t < SS) {
    float mx = -1e30f;
    for (int j = 0; j < SS; ++j) mx = fmaxf(mx, sc[t][j]);
    float sm = 0.f;
    for (int j = 0; j < SS; ++j) { float ev = expf(sc[t][j] - mx); sc[t][j] = ev; sm += ev; }
    float inv = 1.0f / sm;
    for (int j = 0; j < SS; ++j) sc[t][j] *= inv;
  }
  __syncthreads();
  for (int p = t; p < SS * DH; p += 256) {
    int qi = p / DH, d = p - qi * DH;
    float a = 0.f;
    for (int j = 0; j < SS; ++j) a += sc[qi][j] * vs[j * DH + d];
    o[((size_t)(qi * BB + b)) * E + h * DH + d] = a;
  }
}

// ---------------------------------------------------------------------------
// Decoder self-attn, incremental: block per (b,h), 128 threads.
// Writes this position's k,v into cache, attends over positions 0..pos.
// Current-position k/v read from qkv directly (no readback of own writes).
// ---------------------------------------------------------------------------
__global__ void dec_sa_attn_kernel(const float* __restrict__ qkv,
                                   float* __restrict__ Kc, float* __restrict__ Vc,
                                   float* __restrict__ o, int pos) {
  int b = blockIdx.x >> 3, h = blockIdx.x & 7;
  int t = threadIdx.x;
  const float* qp = qkv + (size_t)b * (3 * E) + h * DH;
  const float* kn = qp + E;
  const float* vn = qp + 2 * E;
  float* kc = Kc + ((size_t)pos * BB + b) * E + h * DH;
  float* vc = Vc + ((size_t)pos * BB + b) * E + h * DH;
  __shared__ float qs[DH];
  __shared__ float sc[LBUF];
  if (t < DH) { kc[t] = kn[t]; vc[t] = vn[t]; qs[t] = qp[t]; }
  __syncthreads();
  int L = pos + 1;
  if (t < L) {
    const float* kr = (t == pos) ? kn : (Kc + ((size_t)t * BB + b) * E + h * DH);
    float a = 0.f;
    for (int d = 0; d < DH; ++d) a += qs[d] * kr[d];
    sc[t] = a * 0.125f;
  }
  __syncthreads();
  if (t == 0) {
    float mx = -1e30f;
    for (int j = 0; j < L; ++j) mx = fmaxf(mx, sc[j]);
    float sm = 0.f;
    for (int j = 0; j < L; ++j) { float ev = expf(sc[j] - mx); sc[j] = ev; sm += ev; }
    float inv = 1.0f / sm;
    for (int j = 0; j < L; ++j) sc[j] *= inv;
  }
  __syncthreads();
  if (t < DH) {
    float a = 0.f;
    for (int j = 0; j < L; ++j) {
      const float* vr = (j == pos) ? vn : (Vc + ((size_t)j * BB + b) * E + h * DH);
      a += sc[j] * vr[t];
    }
    o[(size_t)b * E + h * DH + t] = a;
  }
}

// ---------------------------------------------------------------------------
// Decoder cross-attn: block per (b,h), 128 threads, Lk = 24 memory positions.
// ---------------------------------------------------------------------------
__global__ void dec_ca_attn_kernel(const float* __restrict__ q,
                                   const float* __restrict__ Km, const float* __restrict__ Vm,
                                   float* __restrict__ o) {
  int b = blockIdx.x >> 3, h = blockIdx.x & 7;
  int t = threadIdx.x;
  __shared__ float qs[DH];
  __shared__ float sc[SS];
  if (t < DH) qs[t] = q[(size_t)b * E + h * DH + t];
  __syncthreads();
  if (t < SS) {
    const float* kr = Km + ((size_t)t * BB + b) * E + h * DH;
    float a = 0.f;
    for (int d = 0; d < DH; ++d) a += qs[d] * kr[d];
    sc[t] = a * 0.125f;
  }
  __syncthreads();
  if (t == 0) {
    float mx = -1e30f;
    for (int j = 0; j < SS; ++j) mx = fmaxf(mx, sc[j]);
    float sm = 0.f;
    for (int j = 0; j < SS; ++j) { float ev = expf(sc[j] - mx); sc[j] = ev; sm += ev; }
    float inv = 1.0f / sm;
    for (int j = 0; j < SS; ++j) sc[j] *= inv;
  }
  __syncthreads();
  if (t < DH) {
    float a = 0.f;
    for (int j = 0; j < SS; ++j) a += sc[j] * Vm[((size_t)j * BB + b) * E + h * DH + t];
    o[(size_t)b * E + h * DH + t] = a;
  }
}

// ---------------------------------------------------------------------------
__global__ void dec_embed_kernel(const int* __restrict__ tokens, const float* __restrict__ emb,
                                 float* __restrict__ y, int i) {
  int b = blockIdx.x;
  int tok = tokens[i * BB + b];
  const float* er = emb + (size_t)tok * E;
  for (int e = threadIdx.x; e < E; e += blockDim.x) y[(size_t)b * E + e] = er[e];
}

__global__ void dec_init_kernel(int* __restrict__ tokens, unsigned long long* __restrict__ amax) {
  int t = threadIdx.x;
  if (t < BB) { tokens[t] = START_ID; amax[t] = 0ull; }
}

__global__ void next_token_kernel(unsigned long long* __restrict__ amax, int* __restrict__ tokens,
                                  float* __restrict__ outtok, int i) {
  int t = threadIdx.x;
  if (t < BB) {
    unsigned long long p = amax[t];
    int idx = (int)(0xFFFFFFFFu - (unsigned int)(p & 0xFFFFFFFFull));
    tokens[(i + 1) * BB + t] = idx;
    outtok[i * BB + t] = (float)idx;
    amax[t] = 0ull;          // ready for next step
  }
}

// ---------------------------------------------------------------------------
extern "C" void kernel_launch(void* const* d_in, const int* in_sizes, int n_in,
                              void* d_out, int out_size, void* d_ws, size_t ws_size,
                              hipStream_t stream) {
  (void)in_sizes; (void)n_in; (void)out_size; (void)ws_size;
  const int*   inp        = (const int*)d_in[0];
  const float* emb        = (const float*)d_in[1];
  const float* e_aw       = (const float*)d_in[2];
  const float* e_ab       = (const float*)d_in[3];
  const float* e_aow      = (const float*)d_in[4];
  const float* e_aob      = (const float*)d_in[5];
  const float* e_l1g      = (const float*)d_in[6];
  const float* e_l1b      = (const float*)d_in[7];
  const float* e_l2g      = (const float*)d_in[8];
  const float* e_l2b      = (const float*)d_in[9];
  const float* e_f1w      = (const float*)d_in[10];
  const float* e_f1b      = (const float*)d_in[11];
  const float* e_f2w      = (const float*)d_in[12];
  const float* e_f2b      = (const float*)d_in[13];
  const float* e_ng       = (const float*)d_in[14];
  const float* e_nb       = (const float*)d_in[15];
  const float* d_saw      = (const float*)d_in[16];
  const float* d_sab      = (const float*)d_in[17];
  const float* d_saow     = (const float*)d_in[18];
  const float* d_saob     = (const float*)d_in[19];
  const float* d_caw      = (const float*)d_in[20];
  const float* d_cab      = (const float*)d_in[21];
  const float* d_caow     = (const float*)d_in[22];
  const float* d_caob     = (const float*)d_in[23];
  const float* d_l1g      = (const float*)d_in[24];
  const float* d_l1b      = (const float*)d_in[25];
  const float* d_l2g      = (const float*)d_in[26];
  const float* d_l2b      = (const float*)d_in[27];
  const float* d_l3g      = (const float*)d_in[28];
  const float* d_l3b      = (const float*)d_in[29];
  const float* d_f1w      = (const float*)d_in[30];
  const float* d_f1b      = (const float*)d_in[31];
  const float* d_f2w      = (const float*)d_in[32];
  const float* d_f2b      = (const float*)d_in[33];
  const float* d_ng       = (const float*)d_in[34];
  const float* d_nb       = (const float*)d_in[35];
  const float* voc_w      = (const float*)d_in[36];
  const float* voc_b      = (const float*)d_in[37];
  float* out = (float*)d_out;

  // workspace carve-up (floats)
  float* p = (float*)d_ws;
  auto alloc = [&](size_t n) { float* r = p; p += n; return r; };
  float* enc_x   = alloc(192 * 512);
  float* enc_tmp = alloc(192 * 2048);
  float* enc_ao  = alloc(192 * 512);
  float* enc_raw = alloc(192 * 512);
  float* memry   = alloc(192 * 512);
  float* mem_k   = alloc(3 * 192 * 512);
  float* mem_v   = alloc(3 * 192 * 512);
  float* dqkv    = alloc(8 * 1536);
  float* y_in    = alloc(8 * 512);
  float* o_sa    = alloc(8 * 512);
  float* y1raw   = alloc(8 * 512);
  float* y1      = alloc(8 * 512);
  float* qca     = alloc(8 * 512);
  float* oca     = alloc(8 * 512);
  float* y2raw   = alloc(8 * 512);
  float* y2      = alloc(8 * 512);
  float* y3raw   = alloc(8 * 512);
  float* yf      = alloc(8 * 512);
  float* dmid    = alloc(8 * 2048);
  float* cacheK  = alloc(3 * LBUF * 8 * 512);
  float* cacheV  = alloc(3 * LBUF * 8 * 512);
  int* tokens    = (int*)alloc(LBUF * 8);               // 200 ints
  unsigned long long* amax = (unsigned long long*)alloc(16);

  // ---------------- encoder ----------------
  enc_embed_kernel<<<dim3(192), dim3(256), 0, stream>>>(inp, emb, enc_x);
  for (int l = 0; l < NL; ++l) {
    const float* w  = e_aw  + (size_t)l * E * 3 * E;
    const float* bq = e_ab  + (size_t)l * 3 * E;
    const float* ow = e_aow + (size_t)l * E * E;
    const float* ob = e_aob + (size_t)l * E;
    gemm_rows_kernel<<<dim3(192, 6), dim3(256), 0, stream>>>(
        enc_x, E, E, w, 3 * E, bq, nullptr, enc_tmp, 3 * E, 3 * E, 0);
    enc_attn_kernel<<<dim3(64), dim3(256), 0, stream>>>(enc_tmp, enc_ao);
    gemm_rows_kernel<<<dim3(192, 2), dim3(256), 0, stream>>>(
        enc_ao, E, E, ow, E, ob, enc_x, enc_raw, E, E, 0);
    ln_kernel<<<dim3(192), dim3(256), 0, stream>>>(enc_raw, e_l1g + l * E, e_l1b + l * E, enc_x);
    gemm_rows_kernel<<<dim3(192, 8), dim3(256), 0, stream>>>(
        enc_x, E, E, e_f1w + (size_t)l * E * FF, FF, e_f1b + (size_t)l * FF,
        nullptr, enc_tmp, FF, FF, 1);
    gemm_rows_kernel<<<dim3(192, 2), dim3(256), 0, stream>>>(
        enc_tmp, FF, FF, e_f2w + (size_t)l * FF * E, E, e_f2b + (size_t)l * E,
        enc_x, enc_raw, E, E, 0);
    ln_kernel<<<dim3(192), dim3(256), 0, stream>>>(enc_raw, e_l2g + l * E, e_l2b + l * E, enc_x);
  }
  ln_kernel<<<dim3(192), dim3(256), 0, stream>>>(enc_x, e_ng, e_nb, memry);

  // cross-attn K,V for memory (fixed across decode steps)
  for (int l = 0; l < NL; ++l) {
    const float* w  = d_caw + (size_t)l * E * 3 * E;
    const float* bq = d_cab + (size_t)l * 3 * E;
    gemm_rows_kernel<<<dim3(192, 2), dim3(256), 0, stream>>>(
        memry, E, E, w + E, 3 * E, bq + E, nullptr, mem_k + (size_t)l * 192 * 512, E, E, 0);
    gemm_rows_kernel<<<dim3(192, 2), dim3(256), 0, stream>>>(
        memry, E, E, w + 2 * E, 3 * E, bq + 2 * E, nullptr, mem_v + (size_t)l * 192 * 512, E, E, 0);
  }

  // ---------------- greedy decode (KV-cached incremental) ----------------
  dec_init_kernel<<<dim3(1), dim3(64), 0, stream>>>(tokens, amax);
  for (int i = 0; i < ML; ++i) {
    dec_embed_kernel<<<dim3(8), dim3(256), 0, stream>>>(tokens, emb, y_in, i);
    for (int l = 0; l < NL; ++l) {
      const float* saw = d_saw + (size_t)l * E * 3 * E;
      const float* sab = d_sab + (size_t)l * 3 * E;
      const float* caw = d_caw + (size_t)l * E * 3 * E;
      const float* cab = d_cab + (size_t)l * 3 * E;
      float* Kc = cacheK + (size_t)l * LBUF * 8 * 512;
      float* Vc = cacheV + (size_t)l * LBUF * 8 * 512;

      gemm_m8_kernel<<<dim3(6), dim3(256), 0, stream>>>(
          y_in, E, E, saw, 3 * E, sab, nullptr, dqkv, 3 * E, 3 * E, 0, nullptr);
      dec_sa_attn_kernel<<<dim3(64), dim3(128), 0, stream>>>(dqkv, Kc, Vc, o_sa, i);
      gemm_m8_kernel<<<dim3(2), dim3(256), 0, stream>>>(
          o_sa, E, E, d_saow + (size_t)l * E * E, E, d_saob + (size_t)l * E,
          y_in, y1raw, E, E, 0, nullptr);
      ln_kernel<<<dim3(8), dim3(256), 0, stream>>>(y1raw, d_l1g + l * E, d_l1b + l * E, y1);

      gemm_m8_kernel<<<dim3(2), dim3(256), 0, stream>>>(
          y1, E, E, caw, 3 * E, cab, nullptr, qca, E, E, 0, nullptr);
      dec_ca_attn_kernel<<<dim3(64), dim3(128), 0, stream>>>(
          qca, mem_k + (size_t)l * 192 * 512, mem_v + (size_t)l * 192 * 512, oca);
      gemm_m8_kernel<<<dim3(2), dim3(256), 0, stream>>>(
          oca, E, E, d_caow + (size_t)l * E * E, E, d_caob + (size_t)l * E,
          y1, y2raw, E, E, 0, nullptr);
      ln_kernel<<<dim3(8), dim3(256), 0, stream>>>(y2raw, d_l2g + l * E, d_l2b + l * E, y2);

      gemm_m8_kernel<<<dim3(8), dim3(256), 0, stream>>>(
          y2, E, E, d_f1w + (size_t)l * E * FF, FF, d_f1b + (size_t)l * FF,
          nullptr, dmid, FF, FF, 1, nullptr);
      gemm_m8_kernel<<<dim3(2), dim3(256), 0, stream>>>(
          dmid, FF, FF, d_f2w + (size_t)l * FF * E, E, d_f2b + (size_t)l * E,
          y2, y3raw, E, E, 0, nullptr);
      ln_kernel<<<dim3(8), dim3(256), 0, stream>>>(y3raw, d_l3g + l * E, d_l3b + l * E, y_in);
    }
    ln_kernel<<<dim3(8), dim3(256), 0, stream>>>(y_in, d_ng, d_nb, yf);

    // vocab projection -> dists (direct to d_out) + fused argmax
    float* dist_i = out + 192 + (size_t)i * (8 * VTOK);
    gemm_m8_kernel<<<dim3(125), dim3(256), 0, stream>>>(
        yf, E, E, voc_w, VTOK, voc_b, nullptr, dist_i, VTOK, VTOK, 0, amax);
    next_token_kernel<<<dim3(1), dim3(64), 0, stream>>>(amax, tokens, out, i);
  }
}

// Round 2
// 22327.312 us; speedup vs baseline: 1.4863x; 1.4863x over previous
//
#include <hip/hip_runtime.h>
#include <stdint.h>

#define E    512
#define H    8
#define DH   64
#define BB   8
#define SS   24
#define FF   2048
#define NL   3
#define VTOK 32000
#define LBUF 25
#define ML   24
#define START_ID 1

// ---------------------------------------------------------------------------
// Encoder embedding + sinusoidal PE (double to match numpy)
// ---------------------------------------------------------------------------
__global__ void enc_embed_kernel(const int* __restrict__ inp, const float* __restrict__ emb,
                                 float* __restrict__ x) {
  int r = blockIdx.x;
  int s = r / BB, b = r % BB;
  int tok = inp[b * SS + s];
  const float* er = emb + (size_t)tok * E;
  for (int e = threadIdx.x; e < E; e += blockDim.x) {
    int j = e >> 1;
    double dv = exp(-((double)(2 * j)) * (log(10000.0) / (double)E));
    double ang = (double)s * dv;
    double pe = (e & 1) ? cos(ang) : sin(ang);
    x[(size_t)r * E + e] = er[e] + (float)pe;
  }
}

// ---------------------------------------------------------------------------
// Row LayerNorm: grid = rows, block = 256
// ---------------------------------------------------------------------------
__global__ __launch_bounds__(256) void ln_kernel(const float* __restrict__ x,
                          const float* __restrict__ g,
                          const float* __restrict__ bta, float* __restrict__ y) {
  int r = blockIdx.x;
  int t = threadIdx.x;
  const float* xr = x + (size_t)r * E;
  float a0 = xr[t], a1 = xr[t + 256];
  __shared__ float red[256];
  red[t] = a0 + a1;
  __syncthreads();
  for (int s = 128; s > 0; s >>= 1) { if (t < s) red[t] += red[t + s]; __syncthreads(); }
  float m = red[0] * (1.0f / (float)E);
  __syncthreads();
  float d0 = a0 - m, d1 = a1 - m;
  red[t] = d0 * d0 + d1 * d1;
  __syncthreads();
  for (int s = 128; s > 0; s >>= 1) { if (t < s) red[t] += red[t + s]; __syncthreads(); }
  float v = red[0] * (1.0f / (float)E);
  float rstd = 1.0f / sqrtf(v + 1e-5f);
  y[(size_t)r * E + t]       = d0 * rstd * g[t]       + bta[t];
  y[(size_t)r * E + t + 256] = d1 * rstd * g[t + 256] + bta[t + 256];
}

// ---------------------------------------------------------------------------
// 8-row-tiled GEMM: C[row0+m, col] = bias + sum_k A[row0+m,k]*W[k,col] (+resid)(relu)
// A assumed contiguous with lda == K. grid (N/256, Mtiles), block 256.
// Optional fused per-row block argmax -> atomicMax (vocab head).
// ---------------------------------------------------------------------------
template <int K>
__global__ __launch_bounds__(256) void gemm_m8_kernel(const float* __restrict__ A,
                               const float* __restrict__ W, int ldw,
                               const float* __restrict__ bias,
                               const float* __restrict__ resid,
                               float* __restrict__ C, int ldc, int N, int relu,
                               unsigned long long* __restrict__ amax) {
  __shared__ float Al[8 * K];
  int t = threadIdx.x;
  int row0 = blockIdx.y * 8;
  const float4* A4 = (const float4*)(A + (size_t)row0 * K);
  for (int i = t; i < 8 * K / 4; i += 256) ((float4*)Al)[i] = A4[i];
  __syncthreads();
  int col = blockIdx.x * 256 + t;
  float acc[8];
  if (col < N) {
    float bv = bias[col];
#pragma unroll
    for (int m = 0; m < 8; ++m) acc[m] = bv;
    const float* wp = W + col;
#pragma unroll 4
    for (int k = 0; k < K; ++k) {
      float w = wp[(size_t)k * ldw];
#pragma unroll
      for (int m = 0; m < 8; ++m) acc[m] += Al[m * K + k] * w;
    }
#pragma unroll
    for (int m = 0; m < 8; ++m) {
      float v = acc[m];
      if (resid) v += resid[(size_t)(row0 + m) * ldc + col];
      if (relu) v = fmaxf(v, 0.0f);
      acc[m] = v;
      C[(size_t)(row0 + m) * ldc + col] = v;
    }
  }
  if (amax) {
    __syncthreads();
    unsigned long long* red = (unsigned long long*)Al;
    for (int m = 0; m < 8; ++m) {
      unsigned long long key = 0ull;
      if (col < N) {
        unsigned int fb = __float_as_uint(acc[m]);
        fb = (fb & 0x80000000u) ? ~fb : (fb | 0x80000000u);
        key = ((unsigned long long)fb << 32) |
              (unsigned long long)(0xFFFFFFFFu - (unsigned)col);
      }
      red[t] = key;
      __syncthreads();
      for (int s = 128; s > 0; s >>= 1) {
        if (t < s) red[t] = red[t] > red[t + s] ? red[t] : red[t + s];
        __syncthreads();
      }
      if (t == 0) atomicMax(&amax[m], red[0]);
      __syncthreads();
    }
  }
}

// ---------------------------------------------------------------------------
// Encoder self-attention (unchanged): block per (b,h), 256 threads.
// ---------------------------------------------------------------------------
__global__ void enc_attn_kernel(const float* __restrict__ qkv, float* __restrict__ o) {
  int b = blockIdx.x >> 3, h = blockIdx.x & 7;
  __shared__ float qs[SS * DH], ks[SS * DH], vs[SS * DH];
  __shared__ float sc[SS][SS];
  int t = threadIdx.x;
  for (int idx = t; idx < SS * DH; idx += 256) {
    int srow = idx / DH, d = idx - srow * DH;
    size_t base = ((size_t)(srow * BB + b)) * (3 * E) + h * DH + d;
    qs[idx] = qkv[base];
    ks[idx] = qkv[base + E];
    vs[idx] = qkv[base + 2 * E];
  }
  __syncthreads();
  for (int p = t; p < SS * SS; p += 256) {
    int qi = p / SS, kj = p - qi * SS;
    float a = 0.f;
    for (int d = 0; d < DH; ++d) a += qs[qi * DH + d] * ks[kj * DH + d];
    sc[qi][kj] = a * 0.125f;
  }
  __syncthreads();
  if (t < SS) {
    float mx = -1e30f;
    for (int j = 0; j < SS; ++j) mx = fmaxf(mx, sc[t][j]);
    float sm = 0.f;
    for (int j = 0; j < SS; ++j) { float ev = expf(sc[t][j] - mx); sc[t][j] = ev; sm += ev; }
    float inv = 1.0f / sm;
    for (int j = 0; j < SS; ++j) sc[t][j] *= inv;
  }
  __syncthreads();
  for (int p = t; p < SS * DH; p += 256) {
    int qi = p / DH, d = p - qi * DH;
    float a = 0.f;
    for (int j = 0; j < SS; ++j) a += sc[qi][j] * vs[j * DH + d];
    o[((size_t)(qi * BB + b)) * E + h * DH + d] = a;
  }
}

// ---------------------------------------------------------------------------
// Decoder self-attn sublayer, fused: qkv slice GEMM + cache update + attention
// + output-proj partial. grid 64 = (b,h), 192 threads (which = t/64, d = t%64).
// part[b][h][0..511] holds this head's contribution to the output projection.
// ---------------------------------------------------------------------------
__global__ __launch_bounds__(192) void dec_sa_fused(const float* __restrict__ y,
                            const float* __restrict__ saw, const float* __restrict__ sab,
                            float* __restrict__ Kc, float* __restrict__ Vc,
                            const float* __restrict__ prw, float* __restrict__ part,
                            int pos) {
  int b = blockIdx.x >> 3, h = blockIdx.x & 7;
  int t = threadIdx.x;
  int which = t >> 6, d = t & 63;
  __shared__ float yr[E];
  __shared__ float qs[DH], ks[DH], vs[DH], od[DH];
  __shared__ float sc[32];
  if (t < 128) ((float4*)yr)[t] = ((const float4*)(y + (size_t)b * E))[t];
  __syncthreads();
  // qkv slice: col = which*E + h*64 + d
  {
    int col = which * E + h * DH + d;
    float acc = sab[col];
    const float* w0 = saw + col;
#pragma unroll 4
    for (int k = 0; k < E; ++k) acc += yr[k] * w0[(size_t)k * (3 * E)];
    if (which == 0) qs[d] = acc;
    else if (which == 1) { ks[d] = acc; Kc[((size_t)pos * BB + b) * E + h * DH + d] = acc; }
    else                 { vs[d] = acc; Vc[((size_t)pos * BB + b) * E + h * DH + d] = acc; }
  }
  __syncthreads();
  int L = pos + 1;
  if (t < L) {
    float s = 0.f;
    if (t == pos) {
#pragma unroll 8
      for (int j = 0; j < DH; ++j) s += qs[j] * ks[j];
    } else {
      const float* kr = Kc + ((size_t)t * BB + b) * E + h * DH;
#pragma unroll 8
      for (int j = 0; j < DH; ++j) s += qs[j] * kr[j];
    }
    sc[t] = s * 0.125f;
  }
  __syncthreads();
  if (t == 0) {
    float mx = -1e30f;
    for (int j = 0; j < L; ++j) mx = fmaxf(mx, sc[j]);
    float sm = 0.f;
    for (int j = 0; j < L; ++j) { float ev = expf(sc[j] - mx); sc[j] = ev; sm += ev; }
    float inv = 1.0f / sm;
    for (int j = 0; j < L; ++j) sc[j] *= inv;
  }
  __syncthreads();
  if (t < DH) {
    float o = 0.f;
    for (int j = 0; j < L; ++j) {
      float vv = (j == pos) ? vs[d] : Vc[((size_t)j * BB + b) * E + h * DH + d];
      o += sc[j] * vv;
    }
    od[d] = o;
  }
  __syncthreads();
  // output-proj partial over this head's 64 k's, all 512 cols
  float* pp = part + ((size_t)b * H + h) * E;
  for (int c = t; c < E; c += 192) {
    float acc = 0.f;
    const float* w = prw + (size_t)(h * DH) * E + c;
#pragma unroll 8
    for (int kk = 0; kk < DH; ++kk) acc += od[kk] * w[(size_t)kk * E];
    pp[c] = acc;
  }
}

// ---------------------------------------------------------------------------
// Decoder cross-attn sublayer, fused: q slice GEMM + attention over memory
// + output-proj partial. grid 64 = (b,h), 64 threads.
// ---------------------------------------------------------------------------
__global__ __launch_bounds__(64) void dec_ca_fused(const float* __restrict__ y1,
                           const float* __restrict__ caw, const float* __restrict__ cab,
                           const float* __restrict__ Km, const float* __restrict__ Vm,
                           const float* __restrict__ prw, float* __restrict__ part) {
  int b = blockIdx.x >> 3, h = blockIdx.x & 7;
  int d = threadIdx.x;
  __shared__ float yr[E];
  __shared__ float qs[DH], od[DH];
  __shared__ float sc[32];
  ((float4*)yr)[d]      = ((const float4*)(y1 + (size_t)b * E))[d];
  ((float4*)yr)[d + 64] = ((const float4*)(y1 + (size_t)b * E))[d + 64];
  __syncthreads();
  {
    int col = h * DH + d;
    float acc = cab[col];
    const float* w0 = caw + col;
#pragma unroll 4
    for (int k = 0; k < E; ++k) acc += yr[k] * w0[(size_t)k * (3 * E)];
    qs[d] = acc;
  }
  __syncthreads();
  if (d < SS) {
    const float* kr = Km + ((size_t)d * BB + b) * E + h * DH;
    float s = 0.f;
#pragma unroll 8
    for (int j = 0; j < DH; ++j) s += qs[j] * kr[j];
    sc[d] = s * 0.125f;
  }
  __syncthreads();
  if (d == 0) {
    float mx = -1e30f;
    for (int j = 0; j < SS; ++j) mx = fmaxf(mx, sc[j]);
    float sm = 0.f;
    for (int j = 0; j < SS; ++j) { float ev = expf(sc[j] - mx); sc[j] = ev; sm += ev; }
    float inv = 1.0f / sm;
    for (int j = 0; j < SS; ++j) sc[j] *= inv;
  }
  __syncthreads();
  {
    float o = 0.f;
    for (int j = 0; j < SS; ++j) o += sc[j] * Vm[((size_t)j * BB + b) * E + h * DH + d];
    od[d] = o;
  }
  __syncthreads();
  float* pp = part + ((size_t)b * H + h) * E;
  for (int c = d; c < E; c += 64) {
    float acc = 0.f;
    const float* w = prw + (size_t)(h * DH) * E + c;
#pragma unroll 8
    for (int kk = 0; kk < DH; ++kk) acc += od[kk] * w[(size_t)kk * E];
    pp[c] = acc;
  }
}

// ---------------------------------------------------------------------------
// Reduce 8 partials + bias + residual, then LayerNorm. grid 8 (=b), block 256.
// ---------------------------------------------------------------------------
__global__ __launch_bounds__(256) void reduce_ln_kernel(const float* __restrict__ part,
                                 const float* __restrict__ bias,
                                 const float* __restrict__ resid,
                                 const float* __restrict__ g, const float* __restrict__ bta,
                                 float* __restrict__ out) {
  int b = blockIdx.x, t = threadIdx.x;
  float v0 = bias[t]       + resid[(size_t)b * E + t];
  float v1 = bias[t + 256] + resid[(size_t)b * E + t + 256];
  const float* pp = part + (size_t)b * H * E;
#pragma unroll
  for (int j = 0; j < H; ++j) { v0 += pp[j * E + t]; v1 += pp[j * E + t + 256]; }
  __shared__ float red[256];
  red[t] = v0 + v1;
  __syncthreads();
  for (int s = 128; s > 0; s >>= 1) { if (t < s) red[t] += red[t + s]; __syncthreads(); }
  float m = red[0] * (1.0f / (float)E);
  __syncthreads();
  float d0 = v0 - m, d1 = v1 - m;
  red[t] = d0 * d0 + d1 * d1;
  __syncthreads();
  for (int s = 128; s > 0; s >>= 1) { if (t < s) red[t] += red[t + s]; __syncthreads(); }
  float v = red[0] * (1.0f / (float)E);
  float rstd = 1.0f / sqrtf(v + 1e-5f);
  out[(size_t)b * E + t]       = d0 * rstd * g[t]       + bta[t];
  out[(size_t)b * E + t + 256] = d1 * rstd * g[t + 256] + bta[t + 256];
}

// ---------------------------------------------------------------------------
// FFN1 + ReLU: grid 64 = (b, chunk of 256 mid-cols), block 256.
// ---------------------------------------------------------------------------
__global__ __launch_bounds__(256) void dec_ffn1_kernel(const float* __restrict__ y,
                                const float* __restrict__ W1, const float* __restrict__ b1,
                                float* __restrict__ mid) {
  int b = blockIdx.x >> 3, ch = blockIdx.x & 7;
  int t = threadIdx.x;
  __shared__ float yr[E];
  yr[t] = y[(size_t)b * E + t];
  yr[t + 256] = y[(size_t)b * E + t + 256];
  __syncthreads();
  int c = ch * 256 + t;
  float acc = b1[c];
  const float* w = W1 + c;
#pragma unroll 4
  for (int k = 0; k < E; ++k) acc += yr[k] * w[(size_t)k * FF];
  mid[(size_t)b * FF + c] = fmaxf(acc, 0.0f);
}

// ---------------------------------------------------------------------------
// FFN2 split-K partial: grid 64 = (b, kchunk of 256), block 256 (2 cols/thread).
// ---------------------------------------------------------------------------
__global__ __launch_bounds__(256) void dec_ffn2p_kernel(const float* __restrict__ mid,
                                 const float* __restrict__ W2, float* __restrict__ part) {
  int b = blockIdx.x >> 3, ch = blockIdx.x & 7;
  int t = threadIdx.x;
  __shared__ float ml[256];
  ml[t] = mid[(size_t)b * FF + ch * 256 + t];
  __syncthreads();
  float a0 = 0.f, a1 = 0.f;
  const float* w = W2 + (size_t)(ch * 256) * E;
#pragma unroll 4
  for (int k = 0; k < 256; ++k) {
    float m = ml[k];
    a0 += m * w[(size_t)k * E + t];
    a1 += m * w[(size_t)k * E + t + 256];
  }
  float* pp = part + ((size_t)b * H + ch) * E;
  pp[t] = a0;
  pp[t + 256] = a1;
}

// ---------------------------------------------------------------------------
__global__ void dec_embed_kernel(const int* __restrict__ tokens, const float* __restrict__ emb,
                                 float* __restrict__ y, int i) {
  int b = blockIdx.x;
  int tok = tokens[i * BB + b];
  const float* er = emb + (size_t)tok * E;
  for (int e = threadIdx.x; e < E; e += blockDim.x) y[(size_t)b * E + e] = er[e];
}

__global__ void dec_init_kernel(int* __restrict__ tokens, unsigned long long* __restrict__ amax) {
  int t = threadIdx.x;
  if (t < BB) { tokens[t] = START_ID; amax[t] = 0ull; }
}

__global__ void next_token_kernel(unsigned long long* __restrict__ amax, int* __restrict__ tokens,
                                  float* __restrict__ outtok, int i) {
  int t = threadIdx.x;
  if (t < BB) {
    unsigned long long p = amax[t];
    int idx = (int)(0xFFFFFFFFu - (unsigned int)(p & 0xFFFFFFFFull));
    tokens[(i + 1) * BB + t] = idx;
    outtok[i * BB + t] = (float)idx;
    amax[t] = 0ull;
  }
}

// ---------------------------------------------------------------------------
extern "C" void kernel_launch(void* const* d_in, const int* in_sizes, int n_in,
                              void* d_out, int out_size, void* d_ws, size_t ws_size,
                              hipStream_t stream) {
  (void)in_sizes; (void)n_in; (void)out_size; (void)ws_size;
  const int*   inp   = (const int*)d_in[0];
  const float* emb   = (const float*)d_in[1];
  const float* e_aw  = (const float*)d_in[2];
  const float* e_ab  = (const float*)d_in[3];
  const float* e_aow = (const float*)d_in[4];
  const float* e_aob = (const float*)d_in[5];
  const float* e_l1g = (const float*)d_in[6];
  const float* e_l1b = (const float*)d_in[7];
  const float* e_l2g = (const float*)d_in[8];
  const float* e_l2b = (const float*)d_in[9];
  const float* e_f1w = (const float*)d_in[10];
  const float* e_f1b = (const float*)d_in[11];
  const float* e_f2w = (const float*)d_in[12];
  const float* e_f2b = (const float*)d_in[13];
  const float* e_ng  = (const float*)d_in[14];
  const float* e_nb  = (const float*)d_in[15];
  const float* d_saw = (const float*)d_in[16];
  const float* d_sab = (const float*)d_in[17];
  const float* d_saow= (const float*)d_in[18];
  const float* d_saob= (const float*)d_in[19];
  const float* d_caw = (const float*)d_in[20];
  const float* d_cab = (const float*)d_in[21];
  const float* d_caow= (const float*)d_in[22];
  const float* d_caob= (const float*)d_in[23];
  const float* d_l1g = (const float*)d_in[24];
  const float* d_l1b = (const float*)d_in[25];
  const float* d_l2g = (const float*)d_in[26];
  const float* d_l2b = (const float*)d_in[27];
  const float* d_l3g = (const float*)d_in[28];
  const float* d_l3b = (const float*)d_in[29];
  const float* d_f1w = (const float*)d_in[30];
  const float* d_f1b = (const float*)d_in[31];
  const float* d_f2w = (const float*)d_in[32];
  const float* d_f2b = (const float*)d_in[33];
  const float* d_ng  = (const float*)d_in[34];
  const float* d_nb  = (const float*)d_in[35];
  const float* voc_w = (const float*)d_in[36];
  const float* voc_b = (const float*)d_in[37];
  float* out = (float*)d_out;

  // workspace carve-up (floats)
  float* p = (float*)d_ws;
  auto alloc = [&](size_t n) { float* r = p; p += n; return r; };
  float* enc_x   = alloc(192 * 512);
  float* enc_tmp = alloc(192 * 2048);
  float* enc_ao  = alloc(192 * 512);
  float* enc_raw = alloc(192 * 512);
  float* memry   = alloc(192 * 512);
  float* mem_k   = alloc(3 * 192 * 512);
  float* mem_v   = alloc(3 * 192 * 512);
  float* y_in    = alloc(8 * 512);
  float* y1      = alloc(8 * 512);
  float* y2      = alloc(8 * 512);
  float* yf      = alloc(8 * 512);
  float* dmid    = alloc(8 * 2048);
  float* partb   = alloc(8 * 8 * 512);
  float* cacheK  = alloc(3 * LBUF * 8 * 512);
  float* cacheV  = alloc(3 * LBUF * 8 * 512);
  int* tokens    = (int*)alloc(LBUF * 8);
  unsigned long long* amax = (unsigned long long*)alloc(16);

  // ---------------- encoder ----------------
  enc_embed_kernel<<<dim3(192), dim3(256), 0, stream>>>(inp, emb, enc_x);
  for (int l = 0; l < NL; ++l) {
    const float* w  = e_aw  + (size_t)l * E * 3 * E;
    const float* bq = e_ab  + (size_t)l * 3 * E;
    gemm_m8_kernel<512><<<dim3(6, 24), dim3(256), 0, stream>>>(
        enc_x, w, 3 * E, bq, nullptr, enc_tmp, 3 * E, 3 * E, 0, nullptr);
    enc_attn_kernel<<<dim3(64), dim3(256), 0, stream>>>(enc_tmp, enc_ao);
    gemm_m8_kernel<512><<<dim3(2, 24), dim3(256), 0, stream>>>(
        enc_ao, e_aow + (size_t)l * E * E, E, e_aob + (size_t)l * E,
        enc_x, enc_raw, E, E, 0, nullptr);
    ln_kernel<<<dim3(192), dim3(256), 0, stream>>>(enc_raw, e_l1g + l * E, e_l1b + l * E, enc_x);
    gemm_m8_kernel<512><<<dim3(8, 24), dim3(256), 0, stream>>>(
        enc_x, e_f1w + (size_t)l * E * FF, FF, e_f1b + (size_t)l * FF,
        nullptr, enc_tmp, FF, FF, 1, nullptr);
    gemm_m8_kernel<2048><<<dim3(2, 24), dim3(256), 0, stream>>>(
        enc_tmp, e_f2w + (size_t)l * FF * E, E, e_f2b + (size_t)l * E,
        enc_x, enc_raw, E, E, 0, nullptr);
    ln_kernel<<<dim3(192), dim3(256), 0, stream>>>(enc_raw, e_l2g + l * E, e_l2b + l * E, enc_x);
  }
  ln_kernel<<<dim3(192), dim3(256), 0, stream>>>(enc_x, e_ng, e_nb, memry);

  // cross-attn K,V for memory (fixed across decode steps)
  for (int l = 0; l < NL; ++l) {
    const float* w  = d_caw + (size_t)l * E * 3 * E;
    const float* bq = d_cab + (size_t)l * 3 * E;
    gemm_m8_kernel<512><<<dim3(2, 24), dim3(256), 0, stream>>>(
        memry, w + E, 3 * E, bq + E, nullptr, mem_k + (size_t)l * 192 * 512, E, E, 0, nullptr);
    gemm_m8_kernel<512><<<dim3(2, 24), dim3(256), 0, stream>>>(
        memry, w + 2 * E, 3 * E, bq + 2 * E, nullptr, mem_v + (size_t)l * 192 * 512, E, E, 0, nullptr);
  }

  // ---------------- greedy decode (KV-cached incremental) ----------------
  dec_init_kernel<<<dim3(1), dim3(64), 0, stream>>>(tokens, amax);
  for (int i = 0; i < ML; ++i) {
    dec_embed_kernel<<<dim3(8), dim3(256), 0, stream>>>(tokens, emb, y_in, i);
    for (int l = 0; l < NL; ++l) {
      const float* saw = d_saw + (size_t)l * E * 3 * E;
      const float* sab = d_sab + (size_t)l * 3 * E;
      const float* caw = d_caw + (size_t)l * E * 3 * E;
      const float* cab = d_cab + (size_t)l * 3 * E;
      float* Kc = cacheK + (size_t)l * LBUF * 8 * 512;
      float* Vc = cacheV + (size_t)l * LBUF * 8 * 512;

      dec_sa_fused<<<dim3(64), dim3(192), 0, stream>>>(
          y_in, saw, sab, Kc, Vc, d_saow + (size_t)l * E * E, partb, i);
      reduce_ln_kernel<<<dim3(8), dim3(256), 0, stream>>>(
          partb, d_saob + (size_t)l * E, y_in, d_l1g + l * E, d_l1b + l * E, y1);

      dec_ca_fused<<<dim3(64), dim3(64), 0, stream>>>(
          y1, caw, cab, mem_k + (size_t)l * 192 * 512, mem_v + (size_t)l * 192 * 512,
          d_caow + (size_t)l * E * E, partb);
      reduce_ln_kernel<<<dim3(8), dim3(256), 0, stream>>>(
          partb, d_caob + (size_t)l * E, y1, d_l2g + l * E, d_l2b + l * E, y2);

      dec_ffn1_kernel<<<dim3(64), dim3(256), 0, stream>>>(
          y2, d_f1w + (size_t)l * E * FF, d_f1b + (size_t)l * FF, dmid);
      dec_ffn2p_kernel<<<dim3(64), dim3(256), 0, stream>>>(
          dmid, d_f2w + (size_t)l * FF * E, partb);
      reduce_ln_kernel<<<dim3(8), dim3(256), 0, stream>>>(
          partb, d_f2b + (size_t)l * E, y2, d_l3g + l * E, d_l3b + l * E, y_in);
    }
    ln_kernel<<<dim3(8), dim3(256), 0, stream>>>(y_in, d_ng, d_nb, yf);

    float* dist_i = out + 192 + (size_t)i * (8 * VTOK);
    gemm_m8_kernel<512><<<dim3(125, 1), dim3(256), 0, stream>>>(
        yf, voc_w, VTOK, voc_b, nullptr, dist_i, VTOK, VTOK, 0, amax);
    next_token_kernel<<<dim3(1), dim3(64), 0, stream>>>(amax, tokens, out, i);
  }
}

// Round 3
// 6048.515 us; speedup vs baseline: 5.4866x; 3.6914x over previous
//
#include <hip/hip_runtime.h>
#include <stdint.h>

#define E    512
#define H    8
#define DH   64
#define BB   8
#define SS   24
#define FF   2048
#define NL   3
#define VTOK 32000
#define LBUF 25
#define ML   24
#define START_ID 1

// ---------------------------------------------------------------------------
// Encoder embedding + sinusoidal PE (double to match numpy)
// ---------------------------------------------------------------------------
__global__ void enc_embed_kernel(const int* __restrict__ inp, const float* __restrict__ emb,
                                 float* __restrict__ x) {
  int r = blockIdx.x;
  int s = r / BB, b = r % BB;
  int tok = inp[b * SS + s];
  const float* er = emb + (size_t)tok * E;
  for (int e = threadIdx.x; e < E; e += blockDim.x) {
    int j = e >> 1;
    double dv = exp(-((double)(2 * j)) * (log(10000.0) / (double)E));
    double ang = (double)s * dv;
    double pe = (e & 1) ? cos(ang) : sin(ang);
    x[(size_t)r * E + e] = er[e] + (float)pe;
  }
}

// ---------------------------------------------------------------------------
// Row LayerNorm: grid = rows, block = 256
// ---------------------------------------------------------------------------
__global__ __launch_bounds__(256) void ln_kernel(const float* __restrict__ x,
                          const float* __restrict__ g,
                          const float* __restrict__ bta, float* __restrict__ y) {
  int r = blockIdx.x;
  int t = threadIdx.x;
  const float* xr = x + (size_t)r * E;
  float a0 = xr[t], a1 = xr[t + 256];
  __shared__ float red[256];
  red[t] = a0 + a1;
  __syncthreads();
  for (int s = 128; s > 0; s >>= 1) { if (t < s) red[t] += red[t + s]; __syncthreads(); }
  float m = red[0] * (1.0f / (float)E);
  __syncthreads();
  float d0 = a0 - m, d1 = a1 - m;
  red[t] = d0 * d0 + d1 * d1;
  __syncthreads();
  for (int s = 128; s > 0; s >>= 1) { if (t < s) red[t] += red[t + s]; __syncthreads(); }
  float v = red[0] * (1.0f / (float)E);
  float rstd = 1.0f / sqrtf(v + 1e-5f);
  y[(size_t)r * E + t]       = d0 * rstd * g[t]       + bta[t];
  y[(size_t)r * E + t + 256] = d1 * rstd * g[t + 256] + bta[t + 256];
}

// ---------------------------------------------------------------------------
// Fast GEMM: C[M,N] = A[M,K] @ W[K,N(ldw)] (+bias,resid,relu / or partials)
// grid (N/64, S, M/8), block 256. Block: 64 cols, 512-k slice, 8 rows.
// Thread t: tc=t&15 -> cols c0+tc*4 (float4 loads), tk=t>>4 -> k = tk+16i.
// 16-way k-split in block reduced through LDS. S>1 -> write partials [S][M][N].
// Per thread ~8 outstanding float4 loads (unroll 8) -> ~32KB in flight/block.
// ---------------------------------------------------------------------------
__global__ __launch_bounds__(256) void fgemm_kernel(
    const float* __restrict__ A, int K,
    const float* __restrict__ W, int ldw, int N,
    const float* __restrict__ bias,
    const float* __restrict__ resid,
    float* __restrict__ C, int relu,
    unsigned long long* __restrict__ amax) {
  __shared__ float Al[8 * 512];      // 16 KB
  __shared__ float red[16 * 512];    // 32 KB
  int t = threadIdx.x;
  int c0 = blockIdx.x * 64;
  int s = blockIdx.y;
  int row0 = blockIdx.z * 8;
  int kbase = s * 512;
  // A tile: 8 rows x 512 k
  for (int i = t; i < 1024; i += 256) {
    int r = i >> 7, cc = i & 127;
    ((float4*)Al)[i] = *(const float4*)(A + (size_t)(row0 + r) * K + kbase + (cc << 2));
  }
  __syncthreads();
  int tc = t & 15, tk = t >> 4;
  int col = c0 + (tc << 2);
  float acc[8][4];
#pragma unroll
  for (int m = 0; m < 8; ++m) { acc[m][0] = acc[m][1] = acc[m][2] = acc[m][3] = 0.f; }
  const float4* wp = (const float4*)(W + (size_t)kbase * ldw + col);
  const size_t ld4 = (size_t)(ldw >> 2);
#pragma unroll 8
  for (int i = 0; i < 32; ++i) {
    int k = tk + (i << 4);
    float4 wv = wp[(size_t)k * ld4];
#pragma unroll
    for (int m = 0; m < 8; ++m) {
      float a = Al[m * 512 + k];
      acc[m][0] += a * wv.x; acc[m][1] += a * wv.y;
      acc[m][2] += a * wv.z; acc[m][3] += a * wv.w;
    }
  }
  // dump per-tk partials to LDS: red[tk][m*64 + tc*4 ..]
#pragma unroll
  for (int m = 0; m < 8; ++m) {
    float4* rr = (float4*)&red[tk * 512 + m * 64 + (tc << 2)];
    *rr = make_float4(acc[m][0], acc[m][1], acc[m][2], acc[m][3]);
  }
  __syncthreads();
  float out2[2];
#pragma unroll
  for (int j = 0; j < 2; ++j) {
    int o = t + j * 256;
    float v = 0.f;
#pragma unroll
    for (int sl = 0; sl < 16; ++sl) v += red[sl * 512 + o];
    out2[j] = v;
  }
  int S = gridDim.y;
  if (S > 1) {
    // partials: [s][row][col], M = gridDim.z*8
    int M = gridDim.z * 8;
#pragma unroll
    for (int j = 0; j < 2; ++j) {
      int o = t + j * 256; int m = o >> 6, cc = o & 63;
      C[((size_t)s * M + row0 + m) * N + c0 + cc] = out2[j];
    }
  } else {
#pragma unroll
    for (int j = 0; j < 2; ++j) {
      int o = t + j * 256; int m = o >> 6, cc = o & 63;
      int col2 = c0 + cc;
      float v = out2[j] + bias[col2];
      if (resid) v += resid[(size_t)(row0 + m) * N + col2];
      if (relu) v = fmaxf(v, 0.0f);
      C[(size_t)(row0 + m) * N + col2] = v;
      out2[j] = v;
    }
    if (amax) {
      __syncthreads();
      unsigned long long* keys = (unsigned long long*)red;
#pragma unroll
      for (int j = 0; j < 2; ++j) {
        int o = t + j * 256;
        unsigned int fb = __float_as_uint(out2[j]);
        fb = (fb & 0x80000000u) ? ~fb : (fb | 0x80000000u);
        int col2 = c0 + (o & 63);
        keys[o] = ((unsigned long long)fb << 32) |
                  (unsigned long long)(0xFFFFFFFFu - (unsigned)col2);
      }
      __syncthreads();
      if (t < 64) {
        for (int m = 0; m < 8; ++m) {
          unsigned long long k = keys[m * 64 + t];
          for (int off = 32; off; off >>= 1) {
            unsigned long long o2 = __shfl_down(k, off);
            if (o2 > k) k = o2;
          }
          if (t == 0) atomicMax(&amax[m], k);
        }
      }
    }
  }
}

// ---------------------------------------------------------------------------
// Reduce S partial slices + bias + resid (encoder FFN2). grid = M rows.
// ---------------------------------------------------------------------------
__global__ __launch_bounds__(256) void reduce_br_kernel(const float* __restrict__ part, int S, int M,
                                 const float* __restrict__ bias,
                                 const float* __restrict__ resid,
                                 float* __restrict__ outp) {
  int r = blockIdx.x, t = threadIdx.x;
#pragma unroll
  for (int j = 0; j < 2; ++j) {
    int c = t + j * 256;
    float v = bias[c] + resid[(size_t)r * E + c];
    for (int s = 0; s < S; ++s) v += part[((size_t)s * M + r) * E + c];
    outp[(size_t)r * E + c] = v;
  }
}

// ---------------------------------------------------------------------------
// Reduce S partial slices + bias + resid + LayerNorm (decoder FFN2). grid 8.
// ---------------------------------------------------------------------------
__global__ __launch_bounds__(256) void reduce_ln_kernel(const float* __restrict__ part, int S,
                                 const float* __restrict__ bias,
                                 const float* __restrict__ resid,
                                 const float* __restrict__ g, const float* __restrict__ bta,
                                 float* __restrict__ out) {
  int b = blockIdx.x, t = threadIdx.x;
  float v0 = bias[t] + resid[(size_t)b * E + t];
  float v1 = bias[t + 256] + resid[(size_t)b * E + t + 256];
  for (int s = 0; s < S; ++s) {
    v0 += part[((size_t)s * 8 + b) * E + t];
    v1 += part[((size_t)s * 8 + b) * E + t + 256];
  }
  __shared__ float red[256];
  red[t] = v0 + v1;
  __syncthreads();
  for (int s = 128; s > 0; s >>= 1) { if (t < s) red[t] += red[t + s]; __syncthreads(); }
  float m = red[0] * (1.0f / (float)E);
  __syncthreads();
  float d0 = v0 - m, d1 = v1 - m;
  red[t] = d0 * d0 + d1 * d1;
  __syncthreads();
  for (int s = 128; s > 0; s >>= 1) { if (t < s) red[t] += red[t + s]; __syncthreads(); }
  float v = red[0] * (1.0f / (float)E);
  float rstd = 1.0f / sqrtf(v + 1e-5f);
  out[(size_t)b * E + t]       = d0 * rstd * g[t]       + bta[t];
  out[(size_t)b * E + t + 256] = d1 * rstd * g[t + 256] + bta[t + 256];
}

// ---------------------------------------------------------------------------
// Encoder self-attention: block per (b,h), 256 threads.
// ---------------------------------------------------------------------------
__global__ void enc_attn_kernel(const float* __restrict__ qkv, float* __restrict__ o) {
  int b = blockIdx.x >> 3, h = blockIdx.x & 7;
  __shared__ float qs[SS * DH], ks[SS * DH], vs[SS * DH];
  __shared__ float sc[SS][SS];
  int t = threadIdx.x;
  for (int idx = t; idx < SS * DH; idx += 256) {
    int srow = idx / DH, d = idx - srow * DH;
    size_t base = ((size_t)(srow * BB + b)) * (3 * E) + h * DH + d;
    qs[idx] = qkv[base];
    ks[idx] = qkv[base + E];
    vs[idx] = qkv[base + 2 * E];
  }
  __syncthreads();
  for (int p = t; p < SS * SS; p += 256) {
    int qi = p / SS, kj = p - qi * SS;
    float a = 0.f;
    for (int d = 0; d < DH; ++d) a += qs[qi * DH + d] * ks[kj * DH + d];
    sc[qi][kj] = a * 0.125f;
  }
  __syncthreads();
  if (t < SS) {
    float mx = -1e30f;
    for (int j = 0; j < SS; ++j) mx = fmaxf(mx, sc[t][j]);
    float sm = 0.f;
    for (int j = 0; j < SS; ++j) { float ev = expf(sc[t][j] - mx); sc[t][j] = ev; sm += ev; }
    float inv = 1.0f / sm;
    for (int j = 0; j < SS; ++j) sc[t][j] *= inv;
  }
  __syncthreads();
  for (int p = t; p < SS * DH; p += 256) {
    int qi = p / DH, d = p - qi * DH;
    float a = 0.f;
    for (int j = 0; j < SS; ++j) a += sc[qi][j] * vs[j * DH + d];
    o[((size_t)(qi * BB + b)) * E + h * DH + d] = a;
  }
}

// ---------------------------------------------------------------------------
// Decoder self-attn (standalone): grid 64=(b,h), 64 threads.
// qkv row layout [b][3E]. Updates KV cache at pos, attends 0..pos.
// ---------------------------------------------------------------------------
__global__ __launch_bounds__(64) void dec_sa_attn_kernel(const float* __restrict__ qkv,
                                   float* __restrict__ Kc, float* __restrict__ Vc,
                                   float* __restrict__ o, int pos) {
  int b = blockIdx.x >> 3, h = blockIdx.x & 7;
  int t = threadIdx.x;
  const float* qp = qkv + (size_t)b * (3 * E) + h * DH;
  const float* kn = qp + E;
  const float* vn = qp + 2 * E;
  float* kc = Kc + ((size_t)pos * BB + b) * E + h * DH;
  float* vc = Vc + ((size_t)pos * BB + b) * E + h * DH;
  __shared__ float qs[DH];
  __shared__ float sc[32];
  kc[t] = kn[t]; vc[t] = vn[t]; qs[t] = qp[t];
  __syncthreads();
  int L = pos + 1;
  if (t < L) {
    const float* kr = (t == pos) ? kn : (Kc + ((size_t)t * BB + b) * E + h * DH);
    float a = 0.f;
#pragma unroll 8
    for (int d = 0; d < DH; ++d) a += qs[d] * kr[d];
    sc[t] = a * 0.125f;
  }
  __syncthreads();
  if (t == 0) {
    float mx = -1e30f;
    for (int j = 0; j < L; ++j) mx = fmaxf(mx, sc[j]);
    float sm = 0.f;
    for (int j = 0; j < L; ++j) { float ev = expf(sc[j] - mx); sc[j] = ev; sm += ev; }
    float inv = 1.0f / sm;
    for (int j = 0; j < L; ++j) sc[j] *= inv;
  }
  __syncthreads();
  float a = 0.f;
  for (int j = 0; j < L; ++j) {
    const float* vr = (j == pos) ? vn : (Vc + ((size_t)j * BB + b) * E + h * DH);
    a += sc[j] * vr[t];
  }
  o[(size_t)b * E + h * DH + t] = a;
}

// ---------------------------------------------------------------------------
// Decoder cross-attn (standalone): grid 64=(b,h), 64 threads.
// ---------------------------------------------------------------------------
__global__ __launch_bounds__(64) void dec_ca_attn_kernel(const float* __restrict__ q,
                                   const float* __restrict__ Km, const float* __restrict__ Vm,
                                   float* __restrict__ o) {
  int b = blockIdx.x >> 3, h = blockIdx.x & 7;
  int t = threadIdx.x;
  __shared__ float qs[DH];
  __shared__ float sc[SS];
  qs[t] = q[(size_t)b * E + h * DH + t];
  __syncthreads();
  if (t < SS) {
    const float* kr = Km + ((size_t)t * BB + b) * E + h * DH;
    float a = 0.f;
#pragma unroll 8
    for (int d = 0; d < DH; ++d) a += qs[d] * kr[d];
    sc[t] = a * 0.125f;
  }
  __syncthreads();
  if (t == 0) {
    float mx = -1e30f;
    for (int j = 0; j < SS; ++j) mx = fmaxf(mx, sc[j]);
    float sm = 0.f;
    for (int j = 0; j < SS; ++j) { float ev = expf(sc[j] - mx); sc[j] = ev; sm += ev; }
    float inv = 1.0f / sm;
    for (int j = 0; j < SS; ++j) sc[j] *= inv;
  }
  __syncthreads();
  float a = 0.f;
  for (int j = 0; j < SS; ++j) a += sc[j] * Vm[((size_t)j * BB + b) * E + h * DH + t];
  o[(size_t)b * E + h * DH + t] = a;
}

// ---------------------------------------------------------------------------
__global__ void dec_embed_kernel(const int* __restrict__ tokens, const float* __restrict__ emb,
                                 float* __restrict__ y, int i) {
  int b = blockIdx.x;
  int tok = tokens[i * BB + b];
  const float* er = emb + (size_t)tok * E;
  for (int e = threadIdx.x; e < E; e += blockDim.x) y[(size_t)b * E + e] = er[e];
}

__global__ void dec_init_kernel(int* __restrict__ tokens, unsigned long long* __restrict__ amax) {
  int t = threadIdx.x;
  if (t < BB) { tokens[t] = START_ID; amax[t] = 0ull; }
}

__global__ void next_token_kernel(unsigned long long* __restrict__ amax, int* __restrict__ tokens,
                                  float* __restrict__ outtok, int i) {
  int t = threadIdx.x;
  if (t < BB) {
    unsigned long long p = amax[t];
    int idx = (int)(0xFFFFFFFFu - (unsigned int)(p & 0xFFFFFFFFull));
    tokens[(i + 1) * BB + t] = idx;
    outtok[i * BB + t] = (float)idx;
    amax[t] = 0ull;
  }
}

// ---------------------------------------------------------------------------
extern "C" void kernel_launch(void* const* d_in, const int* in_sizes, int n_in,
                              void* d_out, int out_size, void* d_ws, size_t ws_size,
                              hipStream_t stream) {
  (void)in_sizes; (void)n_in; (void)out_size; (void)ws_size;
  const int*   inp   = (const int*)d_in[0];
  const float* emb   = (const float*)d_in[1];
  const float* e_aw  = (const float*)d_in[2];
  const float* e_ab  = (const float*)d_in[3];
  const float* e_aow = (const float*)d_in[4];
  const float* e_aob = (const float*)d_in[5];
  const float* e_l1g = (const float*)d_in[6];
  const float* e_l1b = (const float*)d_in[7];
  const float* e_l2g = (const float*)d_in[8];
  const float* e_l2b = (const float*)d_in[9];
  const float* e_f1w = (const float*)d_in[10];
  const float* e_f1b = (const float*)d_in[11];
  const float* e_f2w = (const float*)d_in[12];
  const float* e_f2b = (const float*)d_in[13];
  const float* e_ng  = (const float*)d_in[14];
  const float* e_nb  = (const float*)d_in[15];
  const float* d_saw = (const float*)d_in[16];
  const float* d_sab = (const float*)d_in[17];
  const float* d_saow= (const float*)d_in[18];
  const float* d_saob= (const float*)d_in[19];
  const float* d_caw = (const float*)d_in[20];
  const float* d_cab = (const float*)d_in[21];
  const float* d_caow= (const float*)d_in[22];
  const float* d_caob= (const float*)d_in[23];
  const float* d_l1g = (const float*)d_in[24];
  const float* d_l1b = (const float*)d_in[25];
  const float* d_l2g = (const float*)d_in[26];
  const float* d_l2b = (const float*)d_in[27];
  const float* d_l3g = (const float*)d_in[28];
  const float* d_l3b = (const float*)d_in[29];
  const float* d_f1w = (const float*)d_in[30];
  const float* d_f1b = (const float*)d_in[31];
  const float* d_f2w = (const float*)d_in[32];
  const float* d_f2b = (const float*)d_in[33];
  const float* d_ng  = (const float*)d_in[34];
  const float* d_nb  = (const float*)d_in[35];
  const float* voc_w = (const float*)d_in[36];
  const float* voc_b = (const float*)d_in[37];
  float* out = (float*)d_out;

  // workspace carve-up (floats)
  float* p = (float*)d_ws;
  auto alloc = [&](size_t n) { float* r = p; p += n; return r; };
  float* enc_x   = alloc(192 * 512);
  float* enc_tmp = alloc(192 * 2048);
  float* enc_ao  = alloc(192 * 512);
  float* enc_raw = alloc(192 * 512);
  float* memry   = alloc(192 * 512);
  float* mem_k   = alloc(3 * 192 * 512);
  float* mem_v   = alloc(3 * 192 * 512);
  float* partE   = alloc(4 * 192 * 512);   // encoder ffn2 partials
  float* dqkv    = alloc(8 * 1536);
  float* y_in    = alloc(8 * 512);
  float* o_sa    = alloc(8 * 512);
  float* y1      = alloc(8 * 512);
  float* y1raw   = alloc(8 * 512);
  float* qca     = alloc(8 * 512);
  float* oca     = alloc(8 * 512);
  float* y2      = alloc(8 * 512);
  float* y2raw   = alloc(8 * 512);
  float* yf      = alloc(8 * 512);
  float* dmid    = alloc(8 * 2048);
  float* partD   = alloc(4 * 8 * 512);     // decoder ffn2 partials
  float* cacheK  = alloc(3 * LBUF * 8 * 512);
  float* cacheV  = alloc(3 * LBUF * 8 * 512);
  int* tokens    = (int*)alloc(LBUF * 8);
  unsigned long long* amax = (unsigned long long*)alloc(16);

  // ---------------- encoder ----------------
  enc_embed_kernel<<<dim3(192), dim3(256), 0, stream>>>(inp, emb, enc_x);
  for (int l = 0; l < NL; ++l) {
    const float* w  = e_aw  + (size_t)l * E * 3 * E;
    const float* bq = e_ab  + (size_t)l * 3 * E;
    fgemm_kernel<<<dim3(24, 1, 24), dim3(256), 0, stream>>>(
        enc_x, E, w, 3 * E, 3 * E, bq, nullptr, enc_tmp, 0, nullptr);
    enc_attn_kernel<<<dim3(64), dim3(256), 0, stream>>>(enc_tmp, enc_ao);
    fgemm_kernel<<<dim3(8, 1, 24), dim3(256), 0, stream>>>(
        enc_ao, E, e_aow + (size_t)l * E * E, E, E, e_aob + (size_t)l * E,
        enc_x, enc_raw, 0, nullptr);
    ln_kernel<<<dim3(192), dim3(256), 0, stream>>>(enc_raw, e_l1g + l * E, e_l1b + l * E, enc_x);
    fgemm_kernel<<<dim3(32, 1, 24), dim3(256), 0, stream>>>(
        enc_x, E, e_f1w + (size_t)l * E * FF, FF, FF, e_f1b + (size_t)l * FF,
        nullptr, enc_tmp, 1, nullptr);
    fgemm_kernel<<<dim3(8, 4, 24), dim3(256), 0, stream>>>(
        enc_tmp, FF, e_f2w + (size_t)l * FF * E, E, E, nullptr,
        nullptr, partE, 0, nullptr);
    reduce_br_kernel<<<dim3(192), dim3(256), 0, stream>>>(
        partE, 4, 192, e_f2b + (size_t)l * E, enc_x, enc_raw);
    ln_kernel<<<dim3(192), dim3(256), 0, stream>>>(enc_raw, e_l2g + l * E, e_l2b + l * E, enc_x);
  }
  ln_kernel<<<dim3(192), dim3(256), 0, stream>>>(enc_x, e_ng, e_nb, memry);

  // cross-attn K,V for memory (fixed across decode steps)
  for (int l = 0; l < NL; ++l) {
    const float* w  = d_caw + (size_t)l * E * 3 * E;
    const float* bq = d_cab + (size_t)l * 3 * E;
    fgemm_kernel<<<dim3(8, 1, 24), dim3(256), 0, stream>>>(
        memry, E, w + E, 3 * E, E, bq + E, nullptr,
        mem_k + (size_t)l * 192 * 512, 0, nullptr);
    fgemm_kernel<<<dim3(8, 1, 24), dim3(256), 0, stream>>>(
        memry, E, w + 2 * E, 3 * E, E, bq + 2 * E, nullptr,
        mem_v + (size_t)l * 192 * 512, 0, nullptr);
  }

  // ---------------- greedy decode (KV-cached incremental) ----------------
  dec_init_kernel<<<dim3(1), dim3(64), 0, stream>>>(tokens, amax);
  for (int i = 0; i < ML; ++i) {
    dec_embed_kernel<<<dim3(8), dim3(256), 0, stream>>>(tokens, emb, y_in, i);
    for (int l = 0; l < NL; ++l) {
      const float* saw = d_saw + (size_t)l * E * 3 * E;
      const float* sab = d_sab + (size_t)l * 3 * E;
      const float* caw = d_caw + (size_t)l * E * 3 * E;
      const float* cab = d_cab + (size_t)l * 3 * E;
      float* Kc = cacheK + (size_t)l * LBUF * 8 * 512;
      float* Vc = cacheV + (size_t)l * LBUF * 8 * 512;

      fgemm_kernel<<<dim3(24, 1, 1), dim3(256), 0, stream>>>(
          y_in, E, saw, 3 * E, 3 * E, sab, nullptr, dqkv, 0, nullptr);
      dec_sa_attn_kernel<<<dim3(64), dim3(64), 0, stream>>>(dqkv, Kc, Vc, o_sa, i);
      fgemm_kernel<<<dim3(8, 1, 1), dim3(256), 0, stream>>>(
          o_sa, E, d_saow + (size_t)l * E * E, E, E, d_saob + (size_t)l * E,
          y_in, y1raw, 0, nullptr);
      ln_kernel<<<dim3(8), dim3(256), 0, stream>>>(y1raw, d_l1g + l * E, d_l1b + l * E, y1);

      fgemm_kernel<<<dim3(8, 1, 1), dim3(256), 0, stream>>>(
          y1, E, caw, 3 * E, E, cab, nullptr, qca, 0, nullptr);
      dec_ca_attn_kernel<<<dim3(64), dim3(64), 0, stream>>>(
          qca, mem_k + (size_t)l * 192 * 512, mem_v + (size_t)l * 192 * 512, oca);
      fgemm_kernel<<<dim3(8, 1, 1), dim3(256), 0, stream>>>(
          oca, E, d_caow + (size_t)l * E * E, E, E, d_caob + (size_t)l * E,
          y1, y2raw, 0, nullptr);
      ln_kernel<<<dim3(8), dim3(256), 0, stream>>>(y2raw, d_l2g + l * E, d_l2b + l * E, y2);

      fgemm_kernel<<<dim3(32, 1, 1), dim3(256), 0, stream>>>(
          y2, E, d_f1w + (size_t)l * E * FF, FF, FF, d_f1b + (size_t)l * FF,
          nullptr, dmid, 1, nullptr);
      fgemm_kernel<<<dim3(8, 4, 1), dim3(256), 0, stream>>>(
          dmid, FF, d_f2w + (size_t)l * FF * E, E, E, nullptr,
          nullptr, partD, 0, nullptr);
      reduce_ln_kernel<<<dim3(8), dim3(256), 0, stream>>>(
          partD, 4, d_f2b + (size_t)l * E, y2, d_l3g + l * E, d_l3b + l * E, y_in);
    }
    ln_kernel<<<dim3(8), dim3(256), 0, stream>>>(y_in, d_ng, d_nb, yf);

    float* dist_i = out + 192 + (size_t)i * (8 * VTOK);
    fgemm_kernel<<<dim3(500, 1, 1), dim3(256), 0, stream>>>(
        yf, E, voc_w, VTOK, VTOK, voc_b, nullptr, dist_i, 0, amax);
    next_token_kernel<<<dim3(1), dim3(64), 0, stream>>>(amax, tokens, out, i);
  }
}